// Round 1
// baseline (502.928 us; speedup 1.0000x reference)
//
#include <hip/hip_runtime.h>
#include <math.h>

// Problem constants (b=2, f=8, c=64, h=256, w=256)
#define BF    16          // b*f
#define CH    64          // channels
#define HW    65536       // h*w
#define SPLIT 4           // partial sums per (bf, c) channel

// ---------------------------------------------------------------------------
// Kernel 1: partial channel sums of nbr.
// grid = BF*CH*SPLIT blocks, 256 threads. Each block sums HW/SPLIT = 16384
// contiguous floats (16 float4 per thread), reduces, writes one partial.
// ---------------------------------------------------------------------------
__global__ __launch_bounds__(256) void ksum_partial_kernel(
    const float* __restrict__ nbr, float* __restrict__ partial) {
    const int blk = blockIdx.x;          // 0 .. BF*CH*SPLIT-1
    const int ch  = blk / SPLIT;         // 0 .. BF*CH-1
    const int s   = blk % SPLIT;
    const int tid = threadIdx.x;

    const float4* base = (const float4*)(nbr + (size_t)ch * HW
                                             + (size_t)s * (HW / SPLIT));
    float sum = 0.f;
#pragma unroll
    for (int k = 0; k < (HW / SPLIT) / (256 * 4); ++k) {   // 16 iters
        float4 v = base[tid + k * 256];
        sum += (v.x + v.y) + (v.z + v.w);
    }
    // wave-64 shuffle reduction
#pragma unroll
    for (int off = 32; off > 0; off >>= 1)
        sum += __shfl_down(sum, off, 64);

    __shared__ float red[4];
    const int lane = tid & 63, wv = tid >> 6;
    if (lane == 0) red[wv] = sum;
    __syncthreads();
    if (tid == 0)
        partial[blk] = (red[0] + red[1]) + (red[2] + red[3]);
}

// ---------------------------------------------------------------------------
// Kernel 2: weight[bf, xy] = sigmoid( sum_c ref[bf, c, xy] * ksum[bf, c] )
// grid = BF * (HW / 1024) = 1024 blocks, 256 threads; 4 pixels (float4) each.
// ---------------------------------------------------------------------------
__global__ __launch_bounds__(256) void weight_kernel(
    const float* __restrict__ ref, const float* __restrict__ partial,
    float* __restrict__ out) {
    const int blocksPerBF = HW / (256 * 4);      // 64
    const int bf      = blockIdx.x / blocksPerBF;
    const int pix_blk = blockIdx.x % blocksPerBF;
    const int tid     = threadIdx.x;

    __shared__ float ks[CH];
    if (tid < CH) {
        float s = 0.f;
#pragma unroll
        for (int p = 0; p < SPLIT; ++p)
            s += partial[((size_t)bf * CH + tid) * SPLIT + p];
        ks[tid] = s;
    }
    __syncthreads();

    const size_t xy0 = (size_t)pix_blk * 1024 + (size_t)tid * 4;
    const float* refbase = ref + (size_t)bf * CH * HW + xy0;

    float4 acc = make_float4(0.f, 0.f, 0.f, 0.f);
#pragma unroll 8
    for (int c = 0; c < CH; ++c) {
        float4 r = *(const float4*)(refbase + (size_t)c * HW);
        const float k = ks[c];
        acc.x = fmaf(r.x, k, acc.x);
        acc.y = fmaf(r.y, k, acc.y);
        acc.z = fmaf(r.z, k, acc.z);
        acc.w = fmaf(r.w, k, acc.w);
    }

    float4 o;
    o.x = 1.f / (1.f + __expf(-acc.x));
    o.y = 1.f / (1.f + __expf(-acc.y));
    o.z = 1.f / (1.f + __expf(-acc.z));
    o.w = 1.f / (1.f + __expf(-acc.w));

    *(float4*)(out + (size_t)bf * HW + xy0) = o;
}

// ---------------------------------------------------------------------------
extern "C" void kernel_launch(void* const* d_in, const int* in_sizes, int n_in,
                              void* d_out, int out_size, void* d_ws, size_t ws_size,
                              hipStream_t stream) {
    const float* nbr = (const float*)d_in[0];
    const float* ref = (const float*)d_in[1];
    float* out       = (float*)d_out;
    float* partial   = (float*)d_ws;   // BF*CH*SPLIT floats = 16 KB

    ksum_partial_kernel<<<BF * CH * SPLIT, 256, 0, stream>>>(nbr, partial);
    weight_kernel<<<BF * (HW / 1024), 256, 0, stream>>>(ref, partial, out);
}

// Round 3
// 473.505 us; speedup vs baseline: 1.0621x; 1.0621x over previous
//
#include <hip/hip_runtime.h>
#include <math.h>

// Problem constants (b=2, f=8, c=64, h=256, w=256)
#define BF    16          // b*f
#define CH    64          // channels
#define HW    65536       // h*w
#define SPLIT 4           // partial sums per (bf, c) channel

// Native clang vector type — required by __builtin_nontemporal_load/store
typedef float vfloat4 __attribute__((ext_vector_type(4)));

// ---------------------------------------------------------------------------
// Kernel 1: partial channel sums of nbr.
// grid = BF*CH*SPLIT = 4096 blocks, 256 threads. Each block sums 16384
// contiguous floats (16 float4 per thread), reduces, writes one partial.
// ---------------------------------------------------------------------------
__global__ __launch_bounds__(256) void ksum_partial_kernel(
    const float* __restrict__ nbr, float* __restrict__ partial) {
    const int blk = blockIdx.x;          // 0 .. BF*CH*SPLIT-1
    const int ch  = blk / SPLIT;         // 0 .. BF*CH-1
    const int s   = blk % SPLIT;
    const int tid = threadIdx.x;

    const vfloat4* base = (const vfloat4*)(nbr + (size_t)ch * HW
                                               + (size_t)s * (HW / SPLIT));
    float sum = 0.f;
#pragma unroll
    for (int k = 0; k < (HW / SPLIT) / (256 * 4); ++k) {   // 16 iters
        vfloat4 v = __builtin_nontemporal_load(&base[tid + k * 256]);
        sum += (v.x + v.y) + (v.z + v.w);
    }
    // wave-64 shuffle reduction
#pragma unroll
    for (int off = 32; off > 0; off >>= 1)
        sum += __shfl_down(sum, off, 64);

    __shared__ float red[4];
    const int lane = tid & 63, wv = tid >> 6;
    if (lane == 0) red[wv] = sum;
    __syncthreads();
    if (tid == 0)
        partial[blk] = (red[0] + red[1]) + (red[2] + red[3]);
}

// ---------------------------------------------------------------------------
// Kernel 2: weight[bf, xy] = sigmoid( sum_c ref[bf, c, xy] * ksum[bf, c] )
// grid = BF * (HW / 1024) = 1024 blocks, 256 threads; 4 pixels (float4) each.
// 2-channel unroll => 16 dwords of load data in flight per thread.
// ---------------------------------------------------------------------------
__global__ __launch_bounds__(256) void weight_kernel(
    const float* __restrict__ ref, const float* __restrict__ partial,
    float* __restrict__ out) {
    const int blocksPerBF = HW / (256 * 4);      // 64
    const int bf      = blockIdx.x / blocksPerBF;
    const int pix_blk = blockIdx.x % blocksPerBF;
    const int tid     = threadIdx.x;

    __shared__ float ks[CH];
    if (tid < CH) {
        float s = 0.f;
#pragma unroll
        for (int p = 0; p < SPLIT; ++p)
            s += partial[((size_t)bf * CH + tid) * SPLIT + p];
        ks[tid] = s;
    }
    __syncthreads();

    const size_t xy0 = (size_t)pix_blk * 1024 + (size_t)tid * 4;
    const float* refbase = ref + (size_t)bf * CH * HW + xy0;

    vfloat4 acc0 = {0.f, 0.f, 0.f, 0.f};
    vfloat4 acc1 = {0.f, 0.f, 0.f, 0.f};
#pragma unroll 8
    for (int c = 0; c < CH; c += 2) {
        vfloat4 r0 = __builtin_nontemporal_load(
            (const vfloat4*)(refbase + (size_t)c * HW));
        vfloat4 r1 = __builtin_nontemporal_load(
            (const vfloat4*)(refbase + (size_t)(c + 1) * HW));
        const float k0 = ks[c], k1 = ks[c + 1];
        acc0.x = fmaf(r0.x, k0, acc0.x);
        acc0.y = fmaf(r0.y, k0, acc0.y);
        acc0.z = fmaf(r0.z, k0, acc0.z);
        acc0.w = fmaf(r0.w, k0, acc0.w);
        acc1.x = fmaf(r1.x, k1, acc1.x);
        acc1.y = fmaf(r1.y, k1, acc1.y);
        acc1.z = fmaf(r1.z, k1, acc1.z);
        acc1.w = fmaf(r1.w, k1, acc1.w);
    }

    vfloat4 o;
    o.x = 1.f / (1.f + __expf(-(acc0.x + acc1.x)));
    o.y = 1.f / (1.f + __expf(-(acc0.y + acc1.y)));
    o.z = 1.f / (1.f + __expf(-(acc0.z + acc1.z)));
    o.w = 1.f / (1.f + __expf(-(acc0.w + acc1.w)));

    __builtin_nontemporal_store(o, (vfloat4*)(out + (size_t)bf * HW + xy0));
}

// ---------------------------------------------------------------------------
extern "C" void kernel_launch(void* const* d_in, const int* in_sizes, int n_in,
                              void* d_out, int out_size, void* d_ws, size_t ws_size,
                              hipStream_t stream) {
    const float* nbr = (const float*)d_in[0];
    const float* ref = (const float*)d_in[1];
    float* out       = (float*)d_out;
    float* partial   = (float*)d_ws;   // BF*CH*SPLIT floats = 16 KB

    ksum_partial_kernel<<<BF * CH * SPLIT, 256, 0, stream>>>(nbr, partial);
    weight_kernel<<<BF * (HW / 1024), 256, 0, stream>>>(ref, partial, out);
}